// Round 1
// baseline (745.703 us; speedup 1.0000x reference)
//
#include <hip/hip_runtime.h>

#define D 64

// ---------------- degree / norm ----------------

__global__ void init_deg_k(int* __restrict__ deg, int N) {
    int i = blockIdx.x * blockDim.x + threadIdx.x;
    if (i < N) deg[i] = 1;  // self-loop
}

__global__ void count_deg_k(const int* __restrict__ dst, int* __restrict__ deg, int E) {
    int e = blockIdx.x * blockDim.x + threadIdx.x;
    if (e < E) atomicAdd(&deg[dst[e]], 1);
}

__global__ void dinv_k(const int* __restrict__ deg, float* __restrict__ dinv, int N) {
    int i = blockIdx.x * blockDim.x + threadIdx.x;
    if (i < N) dinv[i] = rsqrtf((float)deg[i]);
}

// ---------------- dense 64x64 GEMM, wave-per-row ----------------
// out[r][c] = sum_k f(in[r][k]) * W[k][c],  f = relu(v + bias[k]) if relu_bias_in

__global__ __launch_bounds__(256) void gemm64_k(const float* __restrict__ in,
                                                const float* __restrict__ W,
                                                const float* __restrict__ bias,
                                                float* __restrict__ out, int N,
                                                int relu_bias_in) {
    __shared__ float sW[D * D];
    __shared__ float sb[D];
    int t = threadIdx.x;
    for (int i = t; i < D * D; i += 256) sW[i] = W[i];
    if (t < D) sb[t] = bias ? bias[t] : 0.0f;
    __syncthreads();
    int wave = t >> 6;
    int lane = t & 63;
    for (int r = blockIdx.x * 4 + wave; r < N; r += gridDim.x * 4) {
        float v = in[r * D + lane];
        if (relu_bias_in) v = fmaxf(v + sb[lane], 0.0f);
        float acc = 0.0f;
#pragma unroll
        for (int k = 0; k < D; ++k) {
            float a = __shfl(v, k, 64);
            acc = fmaf(a, sW[k * D + lane], acc);
        }
        out[r * D + lane] = acc;
    }
}

// ---------------- aggregation ----------------

// out[i][:] = h[i][:] * dinv[i]^2   (self-loop term; also initializes out)
__global__ void self_init_k(const float* __restrict__ h, const float* __restrict__ dinv,
                            float* __restrict__ out, int total) {
    int tid = blockIdx.x * blockDim.x + threadIdx.x;
    if (tid < total) {
        int i = tid >> 6;
        float di = dinv[i];
        out[tid] = h[tid] * di * di;
    }
}

// one wave per edge: lane c handles feature c
__global__ void scatter_k(const int* __restrict__ src, const int* __restrict__ dst,
                          const float* __restrict__ h, const float* __restrict__ dinv,
                          float* __restrict__ out, int E) {
    int tid = blockIdx.x * blockDim.x + threadIdx.x;
    int e = tid >> 6;
    if (e >= E) return;
    int c = tid & 63;
    int s = src[e];
    int d = dst[e];
    float norm = dinv[s] * dinv[d];
    atomicAdd(&out[d * D + c], h[s * D + c] * norm);
}

__global__ void bias_relu_k(float* __restrict__ out, const float* __restrict__ b, int total) {
    int tid = blockIdx.x * blockDim.x + threadIdx.x;
    if (tid < total) {
        out[tid] = fmaxf(out[tid] + b[tid & 63], 0.0f);
    }
}

// ---------------- launch ----------------

extern "C" void kernel_launch(void* const* d_in, const int* in_sizes, int n_in,
                              void* d_out, int out_size, void* d_ws, size_t ws_size,
                              hipStream_t stream) {
    const float* x  = (const float*)d_in[0];
    const int*   ei = (const int*)d_in[1];
    const float* W1 = (const float*)d_in[2];
    const float* b1 = (const float*)d_in[3];
    const float* W2 = (const float*)d_in[4];
    const float* b2 = (const float*)d_in[5];
    float* out = (float*)d_out;

    int N = in_sizes[0] / D;
    int E = in_sizes[1] / 2;
    const int* src = ei;
    const int* dst = ei + E;

    char* ws = (char*)d_ws;
    int*   deg  = (int*)ws;                                          // N ints
    float* dinv = (float*)(ws + (size_t)N * 4);                      // N floats
    float* bufA = (float*)(ws + (size_t)N * 8);                      // N*64 floats
    float* bufB = (float*)(ws + (size_t)N * 8 + (size_t)N * D * 4);  // N*64 floats

    int nd = N * D;
    dim3 b256(256);

    // shared structural norm
    init_deg_k<<<(N + 255) / 256, b256, 0, stream>>>(deg, N);
    count_deg_k<<<(E + 255) / 256, b256, 0, stream>>>(dst, deg, E);
    dinv_k<<<(N + 255) / 256, b256, 0, stream>>>(deg, dinv, N);

    // layer 1: h1 = x @ W1 -> bufA; agg -> bufB
    gemm64_k<<<2560, b256, 0, stream>>>(x, W1, nullptr, bufA, N, 0);
    self_init_k<<<(nd + 255) / 256, b256, 0, stream>>>(bufA, dinv, bufB, nd);
    scatter_k<<<(E * 64 + 255) / 256, b256, 0, stream>>>(src, dst, bufA, dinv, bufB, E);

    // layer 2: h2 = relu(bufB + b1) @ W2 -> bufA; agg -> out
    gemm64_k<<<2560, b256, 0, stream>>>(bufB, W2, b1, bufA, N, 1);
    self_init_k<<<(nd + 255) / 256, b256, 0, stream>>>(bufA, dinv, out, nd);
    scatter_k<<<(E * 64 + 255) / 256, b256, 0, stream>>>(src, dst, bufA, dinv, out, E);

    // final epilogue: out = relu(out + b2)
    bias_relu_k<<<(nd + 255) / 256, b256, 0, stream>>>(out, b2, nd);
}

// Round 2
// 683.237 us; speedup vs baseline: 1.0914x; 1.0914x over previous
//
#include <hip/hip_runtime.h>

#define D 64

// ---------------- degree / norm ----------------

__global__ void zero_cnt_k(int* __restrict__ cnt, int N) {
    int i = blockIdx.x * blockDim.x + threadIdx.x;
    if (i < N) cnt[i] = 0;
}

__global__ void count_deg_k(const int* __restrict__ dst, int* __restrict__ cnt, int E) {
    int e = blockIdx.x * blockDim.x + threadIdx.x;
    if (e < E) atomicAdd(&cnt[dst[e]], 1);
}

// dinv[i] = rsqrt(cnt[i] + 1)   (self-loop included)
__global__ void dinv_k(const int* __restrict__ cnt, float* __restrict__ dinv, int N) {
    int i = blockIdx.x * blockDim.x + threadIdx.x;
    if (i < N) dinv[i] = rsqrtf((float)cnt[i] + 1.0f);
}

// ---------------- exclusive scan (single block, wave-shfl) ----------------

__global__ __launch_bounds__(1024) void scan_k(const int* __restrict__ cnt,
                                               int* __restrict__ row, int N) {
    __shared__ int wsum[16];
    __shared__ int woff[16];
    int t = threadIdx.x;
    int wave = t >> 6;
    int lane = t & 63;
    int carry = 0;
    for (int base = 0; base < N; base += 1024) {
        int i = base + t;
        int v = (i < N) ? cnt[i] : 0;
        // inclusive wave scan
        int x = v;
#pragma unroll
        for (int off = 1; off < 64; off <<= 1) {
            int y = __shfl_up(x, off, 64);
            if (lane >= off) x += y;
        }
        if (lane == 63) wsum[wave] = x;
        __syncthreads();
        if (wave == 0) {
            int s = (lane < 16) ? wsum[lane] : 0;
#pragma unroll
            for (int off = 1; off < 16; off <<= 1) {
                int y = __shfl_up(s, off, 64);
                if (lane >= off) s += y;
            }
            if (lane < 16) woff[lane] = s;  // inclusive scan of wave sums
        }
        __syncthreads();
        int waveoff = (wave > 0) ? woff[wave - 1] : 0;
        int excl = x + waveoff - v;
        if (i < N) row[i] = carry + excl;
        int total = woff[15];
        __syncthreads();  // protect wsum/woff before next chunk
        carry += total;
    }
    if (t == 0) row[N] = carry;
}

__global__ void copy_cur_k(const int* __restrict__ row, int* __restrict__ cur, int N) {
    int i = blockIdx.x * blockDim.x + threadIdx.x;
    if (i < N) cur[i] = row[i];
}

// CSR fill: srcs[pos] = src, w[pos] = dinv[src]*dinv[dst]
__global__ void fill_k(const int* __restrict__ src, const int* __restrict__ dst,
                       const float* __restrict__ dinv, int* __restrict__ cur,
                       int* __restrict__ srcs, float* __restrict__ w, int E) {
    int e = blockIdx.x * blockDim.x + threadIdx.x;
    if (e >= E) return;
    int s = src[e];
    int d = dst[e];
    int pos = atomicAdd(&cur[d], 1);
    srcs[pos] = s;
    w[pos] = dinv[s] * dinv[d];
}

// ---------------- fused layer: out = relu( (A_norm @ in) @ W + b ) ----------------
// wave per node; lane = feature

__global__ __launch_bounds__(256) void layer_k(const float* __restrict__ in,
                                               const int* __restrict__ row,
                                               const int* __restrict__ srcs,
                                               const float* __restrict__ w,
                                               const float* __restrict__ dinv,
                                               const float* __restrict__ W,
                                               const float* __restrict__ b,
                                               float* __restrict__ out, int N) {
    __shared__ float sW[D * D];
    __shared__ float sb[D];
    int t = threadIdx.x;
    for (int i = t; i < D * D; i += 256) sW[i] = W[i];
    if (t < D) sb[t] = b[t];
    __syncthreads();
    int lane = t & 63;
    int wid = blockIdx.x * 4 + (t >> 6);
    int nw = gridDim.x * 4;
    for (int i = wid; i < N; i += nw) {
        float di = dinv[i];
        float v = in[(size_t)i * D + lane] * di * di;  // self-loop term
        int beg = row[i], end = row[i + 1];
        for (int j = beg; j < end; ++j) {
            v = fmaf(in[(size_t)srcs[j] * D + lane], w[j], v);
        }
        // GEMM epilogue: acc[c] = sum_k v[k] * W[k][c]  + bias, relu
        float acc = sb[lane];
#pragma unroll
        for (int k = 0; k < D; ++k) {
            acc = fmaf(__shfl(v, k, 64), sW[k * D + lane], acc);
        }
        out[(size_t)i * D + lane] = fmaxf(acc, 0.0f);
    }
}

// ---------------- launch ----------------

extern "C" void kernel_launch(void* const* d_in, const int* in_sizes, int n_in,
                              void* d_out, int out_size, void* d_ws, size_t ws_size,
                              hipStream_t stream) {
    const float* x  = (const float*)d_in[0];
    const int*   ei = (const int*)d_in[1];
    const float* W1 = (const float*)d_in[2];
    const float* b1 = (const float*)d_in[3];
    const float* W2 = (const float*)d_in[4];
    const float* b2 = (const float*)d_in[5];
    float* out = (float*)d_out;

    int N = in_sizes[0] / D;
    int E = in_sizes[1] / 2;
    const int* src = ei;
    const int* dst = ei + E;

    // workspace layout
    char* ws = (char*)d_ws;
    size_t off = 0;
    int* cnt = (int*)(ws + off);    off += (size_t)N * 4;
    int* row = (int*)(ws + off);    off += (size_t)(N + 1) * 4;
    int* cur = (int*)(ws + off);    off += (size_t)N * 4;
    float* dinv = (float*)(ws + off); off += (size_t)N * 4;
    int* srcs = (int*)(ws + off);   off += (size_t)E * 4;
    float* w = (float*)(ws + off);  off += (size_t)E * 4;
    float* buf = (float*)(ws + off);  // N*D floats

    dim3 b256(256);

    // CSR build (structural, shared by both layers)
    zero_cnt_k<<<(N + 255) / 256, b256, 0, stream>>>(cnt, N);
    count_deg_k<<<(E + 255) / 256, b256, 0, stream>>>(dst, cnt, E);
    dinv_k<<<(N + 255) / 256, b256, 0, stream>>>(cnt, dinv, N);
    scan_k<<<1, 1024, 0, stream>>>(cnt, row, N);
    copy_cur_k<<<(N + 255) / 256, b256, 0, stream>>>(row, cur, N);
    fill_k<<<(E + 255) / 256, b256, 0, stream>>>(src, dst, dinv, cur, srcs, w, E);

    // layer 1: buf = relu( (A @ x) @ W1 + b1 )
    layer_k<<<2560, b256, 0, stream>>>(x, row, srcs, w, dinv, W1, b1, buf, N);
    // layer 2: out = relu( (A @ buf) @ W2 + b2 )
    layer_k<<<2560, b256, 0, stream>>>(buf, row, srcs, w, dinv, W2, b2, out, N);
}

// Round 3
// 435.926 us; speedup vs baseline: 1.7106x; 1.5673x over previous
//
#include <hip/hip_runtime.h>

#define D 64

// ---------------- zero a contiguous int4 region ----------------
__global__ void zero4_k(int4* __restrict__ p, long n4) {
    long i = (long)blockIdx.x * blockDim.x + threadIdx.x;
    if (i < n4) p[i] = make_int4(0, 0, 0, 0);
}

// ---------------- degree count ----------------
__global__ void count_deg_k(const int* __restrict__ dst, int* __restrict__ cnt, int E) {
    int e = blockIdx.x * blockDim.x + threadIdx.x;
    if (e < E) atomicAdd(&cnt[dst[e]], 1);
}

// ---------------- grid scan of padded counts ----------------
// pass 1: per-block (1024-chunk) exclusive scan of pcnt=(cnt+7)&~7 into row,
//         block total into partials[b]
__global__ __launch_bounds__(1024) void scan1_k(const int* __restrict__ cnt,
                                                int* __restrict__ row,
                                                int* __restrict__ partials, int N) {
    __shared__ int wsum[16];
    int t = threadIdx.x, wave = t >> 6, lane = t & 63;
    int i = blockIdx.x * 1024 + t;
    int v = (i < N) ? ((cnt[i] + 7) & ~7) : 0;
    int x = v;
#pragma unroll
    for (int off = 1; off < 64; off <<= 1) {
        int y = __shfl_up(x, off, 64);
        if (lane >= off) x += y;
    }
    if (lane == 63) wsum[wave] = x;
    __syncthreads();
    if (wave == 0) {
        int s = (lane < 16) ? wsum[lane] : 0;
#pragma unroll
        for (int off = 1; off < 16; off <<= 1) {
            int y = __shfl_up(s, off, 64);
            if (lane >= off) s += y;
        }
        if (lane < 16) wsum[lane] = s;  // inclusive scan of wave sums
    }
    __syncthreads();
    int woff = (wave > 0) ? wsum[wave - 1] : 0;
    if (i < N) row[i] = x + woff - v;  // block-local exclusive
    if (t == 0) partials[blockIdx.x] = wsum[15];
}

// pass 2: scan the (<=128) block totals; write grand total to row[N]
__global__ __launch_bounds__(128) void scan2_k(const int* __restrict__ partials,
                                               int* __restrict__ blockoff,
                                               int* __restrict__ rowN, int nb) {
    __shared__ int s[128];
    int t = threadIdx.x;
    int v = (t < nb) ? partials[t] : 0;
    s[t] = v;
    __syncthreads();
    for (int off = 1; off < 128; off <<= 1) {
        int add = (t >= off) ? s[t - off] : 0;
        __syncthreads();
        s[t] += add;
        __syncthreads();
    }
    blockoff[t] = s[t] - v;  // exclusive
    if (t == nb - 1) *rowN = s[t];
}

// pass 3: add block offsets; init cursor; compute dinv
__global__ void scan3_k(int* __restrict__ row, int* __restrict__ cur,
                        const int* __restrict__ blockoff,
                        const int* __restrict__ cnt, float* __restrict__ dinv, int N) {
    int i = blockIdx.x * blockDim.x + threadIdx.x;
    if (i < N) {
        int r = row[i] + blockoff[i >> 10];
        row[i] = r;
        cur[i] = r;
        dinv[i] = rsqrtf((float)cnt[i] + 1.0f);
    }
}

// ---------------- CSR fill (pad slots stay {src=0, w=0} from zeroing) ----------------
__global__ void fill_k(const int* __restrict__ src, const int* __restrict__ dst,
                       const float* __restrict__ dinv, int* __restrict__ cur,
                       int* __restrict__ srcs, float* __restrict__ ew, int E) {
    int e = blockIdx.x * blockDim.x + threadIdx.x;
    if (e >= E) return;
    int s = src[e];
    int d = dst[e];
    int pos = atomicAdd(&cur[d], 1);
    srcs[pos] = s;
    ew[pos] = dinv[s] * dinv[d];
}

// ---------------- fused layer: out = relu( (A_norm @ in) @ W + b ) ----------------
// wave per node; lane = feature. Rows padded to multiples of 8 -> aligned int4 loads.
__global__ __launch_bounds__(256) void layer_k(const float* __restrict__ in,
                                               const int* __restrict__ row,
                                               const int* __restrict__ srcs,
                                               const float* __restrict__ ew,
                                               const float* __restrict__ dinv,
                                               const float* __restrict__ W,
                                               const float* __restrict__ b,
                                               float* __restrict__ out, int N) {
    __shared__ float sW[D * D];
    __shared__ float sb[D];
    int t = threadIdx.x;
    for (int i = t; i < D * D; i += 256) sW[i] = W[i];
    if (t < D) sb[t] = b[t];
    __syncthreads();
    int lane = t & 63;
    int wid = blockIdx.x * 4 + (t >> 6);
    int nw = gridDim.x * 4;
    for (int i = wid; i < N; i += nw) {
        float di = dinv[i];
        float v0 = in[(size_t)i * D + lane] * di * di;  // self-loop term
        float v1 = 0.f, v2 = 0.f, v3 = 0.f;
        int beg = row[i], end = row[i + 1];
        for (int j = beg; j < end; j += 8) {
            int4 sa = *(const int4*)(srcs + j);
            int4 sb4 = *(const int4*)(srcs + j + 4);
            float4 wa = *(const float4*)(ew + j);
            float4 wb = *(const float4*)(ew + j + 4);
            v0 = fmaf(in[(size_t)sa.x * D + lane], wa.x, v0);
            v1 = fmaf(in[(size_t)sa.y * D + lane], wa.y, v1);
            v2 = fmaf(in[(size_t)sa.z * D + lane], wa.z, v2);
            v3 = fmaf(in[(size_t)sa.w * D + lane], wa.w, v3);
            v0 = fmaf(in[(size_t)sb4.x * D + lane], wb.x, v0);
            v1 = fmaf(in[(size_t)sb4.y * D + lane], wb.y, v1);
            v2 = fmaf(in[(size_t)sb4.z * D + lane], wb.z, v2);
            v3 = fmaf(in[(size_t)sb4.w * D + lane], wb.w, v3);
        }
        float v = (v0 + v1) + (v2 + v3);
        // GEMM epilogue: acc[c] = sum_k v[k] * W[k][c] + bias, relu
        float a0 = sb[lane], a1 = 0.f, a2 = 0.f, a3 = 0.f;
#pragma unroll
        for (int k = 0; k < D; k += 4) {
            a0 = fmaf(__shfl(v, k, 64), sW[k * D + lane], a0);
            a1 = fmaf(__shfl(v, k + 1, 64), sW[(k + 1) * D + lane], a1);
            a2 = fmaf(__shfl(v, k + 2, 64), sW[(k + 2) * D + lane], a2);
            a3 = fmaf(__shfl(v, k + 3, 64), sW[(k + 3) * D + lane], a3);
        }
        out[(size_t)i * D + lane] = fmaxf((a0 + a1) + (a2 + a3), 0.0f);
    }
}

// ---------------- launch ----------------

extern "C" void kernel_launch(void* const* d_in, const int* in_sizes, int n_in,
                              void* d_out, int out_size, void* d_ws, size_t ws_size,
                              hipStream_t stream) {
    const float* x  = (const float*)d_in[0];
    const int*   ei = (const int*)d_in[1];
    const float* W1 = (const float*)d_in[2];
    const float* b1 = (const float*)d_in[3];
    const float* W2 = (const float*)d_in[4];
    const float* b2 = (const float*)d_in[5];
    float* out = (float*)d_out;

    int N = in_sizes[0] / D;
    int E = in_sizes[1] / 2;
    const int* src = ei;
    const int* dst = ei + E;

    int Emax = E + 7 * N + 16;  // padded-CSR upper bound, multiple of 16

    // workspace layout (all offsets 16B-aligned; cnt|srcs|ew contiguous zero-zone)
    char* ws = (char*)d_ws;
    size_t off = 0;
    auto align16 = [](size_t v) { return (v + 15) & ~(size_t)15; };
    int* cnt = (int*)(ws + off);      off += align16((size_t)N * 4);
    int* srcs = (int*)(ws + off);     off += align16((size_t)Emax * 4);
    float* ew = (float*)(ws + off);   off += align16((size_t)Emax * 4);
    size_t zone_bytes = off;          // cnt + srcs + ew
    int* row = (int*)(ws + off);      off += align16((size_t)(N + 1) * 4);
    int* cur = (int*)(ws + off);      off += align16((size_t)N * 4);
    float* dinv = (float*)(ws + off); off += align16((size_t)N * 4);
    int* partials = (int*)(ws + off); off += 512;
    int* blockoff = (int*)(ws + off); off += 512;
    float* buf = (float*)(ws + off);  // N*D floats

    dim3 b256(256);
    int nb = (N + 1023) / 1024;  // scan blocks (<=128)

    long zone4 = (long)(zone_bytes / 16);
    zero4_k<<<(int)((zone4 + 255) / 256), b256, 0, stream>>>((int4*)ws, zone4);
    count_deg_k<<<(E + 255) / 256, b256, 0, stream>>>(dst, cnt, E);
    scan1_k<<<nb, 1024, 0, stream>>>(cnt, row, partials, N);
    scan2_k<<<1, 128, 0, stream>>>(partials, blockoff, row + N, nb);
    scan3_k<<<(N + 255) / 256, b256, 0, stream>>>(row, cur, blockoff, cnt, dinv, N);
    fill_k<<<(E + 255) / 256, b256, 0, stream>>>(src, dst, dinv, cur, srcs, ew, E);

    // layer 1: buf = relu( (A @ x) @ W1 + b1 )
    layer_k<<<2560, b256, 0, stream>>>(x, row, srcs, ew, dinv, W1, b1, buf, N);
    // layer 2: out = relu( (A @ buf) @ W2 + b2 )
    layer_k<<<2560, b256, 0, stream>>>(buf, row, srcs, ew, dinv, W2, b2, out, N);
}

// Round 4
// 418.742 us; speedup vs baseline: 1.7808x; 1.0410x over previous
//
#include <hip/hip_runtime.h>

#define D 64

typedef unsigned int u32;
typedef unsigned short u16;

__device__ __forceinline__ float bf_lo(u32 p) { return __uint_as_float(p << 16); }
__device__ __forceinline__ float bf_hi(u32 p) { return __uint_as_float(p & 0xffff0000u); }
__device__ __forceinline__ u32 bf_rne(float f) {
    u32 u = __float_as_uint(f);
    return (u + 0x7fffu + ((u >> 16) & 1u)) >> 16;
}

// ---------------- zero a contiguous int4 region ----------------
__global__ void zero4_k(int4* __restrict__ p, long n4) {
    long i = (long)blockIdx.x * blockDim.x + threadIdx.x;
    if (i < n4) p[i] = make_int4(0, 0, 0, 0);
}

// ---------------- fp32 -> packed bf16 cast (4 floats / thread) ----------------
__global__ void xcast_k(const float4* __restrict__ x, uint2* __restrict__ xb, int n4) {
    int i = blockIdx.x * blockDim.x + threadIdx.x;
    if (i < n4) {
        float4 v = x[i];
        uint2 o;
        o.x = bf_rne(v.x) | (bf_rne(v.y) << 16);
        o.y = bf_rne(v.z) | (bf_rne(v.w) << 16);
        xb[i] = o;
    }
}

// ---------------- degree count ----------------
__global__ void count_deg_k(const int* __restrict__ dst, int* __restrict__ cnt, int E) {
    int e = blockIdx.x * blockDim.x + threadIdx.x;
    if (e < E) atomicAdd(&cnt[dst[e]], 1);
}

// ---------------- grid scan of padded counts ----------------
__global__ __launch_bounds__(1024) void scan1_k(const int* __restrict__ cnt,
                                                int* __restrict__ row,
                                                int* __restrict__ partials, int N) {
    __shared__ int wsum[16];
    int t = threadIdx.x, wave = t >> 6, lane = t & 63;
    int i = blockIdx.x * 1024 + t;
    int v = (i < N) ? ((cnt[i] + 7) & ~7) : 0;
    int x = v;
#pragma unroll
    for (int off = 1; off < 64; off <<= 1) {
        int y = __shfl_up(x, off, 64);
        if (lane >= off) x += y;
    }
    if (lane == 63) wsum[wave] = x;
    __syncthreads();
    if (wave == 0) {
        int s = (lane < 16) ? wsum[lane] : 0;
#pragma unroll
        for (int off = 1; off < 16; off <<= 1) {
            int y = __shfl_up(s, off, 64);
            if (lane >= off) s += y;
        }
        if (lane < 16) wsum[lane] = s;
    }
    __syncthreads();
    int woff = (wave > 0) ? wsum[wave - 1] : 0;
    if (i < N) row[i] = x + woff - v;
    if (t == 0) partials[blockIdx.x] = wsum[15];
}

__global__ __launch_bounds__(128) void scan2_k(const int* __restrict__ partials,
                                               int* __restrict__ blockoff,
                                               int* __restrict__ rowN, int nb) {
    __shared__ int s[128];
    int t = threadIdx.x;
    int v = (t < nb) ? partials[t] : 0;
    s[t] = v;
    __syncthreads();
    for (int off = 1; off < 128; off <<= 1) {
        int add = (t >= off) ? s[t - off] : 0;
        __syncthreads();
        s[t] += add;
        __syncthreads();
    }
    blockoff[t] = s[t] - v;
    if (t == nb - 1) *rowN = s[t];
}

__global__ void scan3_k(int* __restrict__ row, int* __restrict__ cur,
                        const int* __restrict__ blockoff,
                        const int* __restrict__ cnt, float* __restrict__ dinv, int N) {
    int i = blockIdx.x * blockDim.x + threadIdx.x;
    if (i < N) {
        int r = row[i] + blockoff[i >> 10];
        row[i] = r;
        cur[i] = r;
        dinv[i] = rsqrtf((float)cnt[i] + 1.0f);
    }
}

// ---------------- CSR fill (pad slots stay {src=0, w=0} from zeroing) ----------------
__global__ void fill_k(const int* __restrict__ src, const int* __restrict__ dst,
                       const float* __restrict__ dinv, int* __restrict__ cur,
                       int* __restrict__ srcs, float* __restrict__ ew, int E) {
    int e = blockIdx.x * blockDim.x + threadIdx.x;
    if (e >= E) return;
    int s = src[e];
    int d = dst[e];
    int pos = atomicAdd(&cur[d], 1);
    srcs[pos] = s;
    ew[pos] = dinv[s] * dinv[d];
}

// ---------------- fused layer: out = relu( (A_norm @ in) @ W + b ) ----------------
// wave per node. Gather: lanes 0-31 = edge j, lanes 32-63 = edge j+1; each lane
// loads a bf16x2 (2 features). Epilogue: feature k lives in component k&1 of
// lane k>>1 (lanes 0-31 hold combined sums).
__global__ __launch_bounds__(256) void layer_k(const u32* __restrict__ inb,
                                               const int* __restrict__ row,
                                               const int* __restrict__ srcs,
                                               const float* __restrict__ ew,
                                               const float* __restrict__ dinv,
                                               const float* __restrict__ W,
                                               const float* __restrict__ b,
                                               float* __restrict__ out_f32,
                                               u16* __restrict__ out_b16, int N) {
    __shared__ float sW[D * D];
    __shared__ float sbias[D];
    int t = threadIdx.x;
    for (int i = t; i < D * D; i += 256) sW[i] = W[i];
    if (t < D) sbias[t] = b[t];
    __syncthreads();
    int lane = t & 63;
    int laneL = lane & 31;
    int h = lane >> 5;
    int wid = blockIdx.x * 4 + (t >> 6);
    int nw = gridDim.x * 4;
    for (int i = wid; i < N; i += nw) {
        float di = dinv[i];
        float wself = h ? 0.0f : di * di;
        u32 ps = inb[i * 32 + laneL];  // self-loop row
        float vx = bf_lo(ps) * wself;
        float vy = bf_hi(ps) * wself;
        float ux = 0.f, uy = 0.f;
        int beg = row[i], end = row[i + 1];
        for (int j = beg; j < end; j += 8) {
            int4 sa = *(const int4*)(srcs + j);
            int4 sbv = *(const int4*)(srcs + j + 4);
            float4 wa = *(const float4*)(ew + j);
            float4 wb = *(const float4*)(ew + j + 4);
            int s0 = h ? sa.y : sa.x;    float w0 = h ? wa.y : wa.x;
            int s1 = h ? sa.w : sa.z;    float w1 = h ? wa.w : wa.z;
            int s2 = h ? sbv.y : sbv.x;  float w2 = h ? wb.y : wb.x;
            int s3 = h ? sbv.w : sbv.z;  float w3 = h ? wb.w : wb.z;
            u32 p0 = inb[s0 * 32 + laneL];
            u32 p1 = inb[s1 * 32 + laneL];
            u32 p2 = inb[s2 * 32 + laneL];
            u32 p3 = inb[s3 * 32 + laneL];
            vx = fmaf(bf_lo(p0), w0, vx);
            vy = fmaf(bf_hi(p0), w0, vy);
            ux = fmaf(bf_lo(p1), w1, ux);
            uy = fmaf(bf_hi(p1), w1, uy);
            vx = fmaf(bf_lo(p2), w2, vx);
            vy = fmaf(bf_hi(p2), w2, vy);
            ux = fmaf(bf_lo(p3), w3, ux);
            uy = fmaf(bf_hi(p3), w3, uy);
        }
        vx += ux;
        vy += uy;
        // combine halves: lanes 0..31 pick up lanes 32..63's partials
        vx += __shfl(vx, laneL + 32, 64);
        vy += __shfl(vy, laneL + 32, 64);
        // GEMM epilogue
        float a0 = sbias[lane], a1 = 0.f, a2 = 0.f, a3 = 0.f;
#pragma unroll
        for (int q = 0; q < 32; q += 2) {
            float fx0 = __shfl(vx, q, 64);
            float fy0 = __shfl(vy, q, 64);
            float fx1 = __shfl(vx, q + 1, 64);
            float fy1 = __shfl(vy, q + 1, 64);
            a0 = fmaf(fx0, sW[(2 * q + 0) * D + lane], a0);
            a1 = fmaf(fy0, sW[(2 * q + 1) * D + lane], a1);
            a2 = fmaf(fx1, sW[(2 * q + 2) * D + lane], a2);
            a3 = fmaf(fy1, sW[(2 * q + 3) * D + lane], a3);
        }
        float acc = fmaxf((a0 + a1) + (a2 + a3), 0.0f);
        if (out_b16) {
            out_b16[(size_t)i * D + lane] = (u16)bf_rne(acc);
        } else {
            out_f32[(size_t)i * D + lane] = acc;
        }
    }
}

// ---------------- launch ----------------

extern "C" void kernel_launch(void* const* d_in, const int* in_sizes, int n_in,
                              void* d_out, int out_size, void* d_ws, size_t ws_size,
                              hipStream_t stream) {
    const float* x  = (const float*)d_in[0];
    const int*   ei = (const int*)d_in[1];
    const float* W1 = (const float*)d_in[2];
    const float* b1 = (const float*)d_in[3];
    const float* W2 = (const float*)d_in[4];
    const float* b2 = (const float*)d_in[5];
    float* out = (float*)d_out;

    int N = in_sizes[0] / D;
    int E = in_sizes[1] / 2;
    const int* src = ei;
    const int* dst = ei + E;

    int Emax = E + 7 * N + 16;

    char* ws = (char*)d_ws;
    size_t off = 0;
    auto align256 = [](size_t v) { return (v + 255) & ~(size_t)255; };
    int* cnt = (int*)(ws + off);      off += align256((size_t)N * 4);
    int* srcs = (int*)(ws + off);     off += align256((size_t)Emax * 4);
    float* ew = (float*)(ws + off);   off += align256((size_t)Emax * 4);
    size_t zone_bytes = off;          // cnt + srcs + ew zeroed together
    int* row = (int*)(ws + off);      off += align256((size_t)(N + 1) * 4);
    int* cur = (int*)(ws + off);      off += align256((size_t)N * 4);
    float* dinv = (float*)(ws + off); off += align256((size_t)N * 4);
    int* partials = (int*)(ws + off); off += 512;
    int* blockoff = (int*)(ws + off); off += 512;
    u32* xb = (u32*)(ws + off);       off += align256((size_t)N * D * 2);  // x as bf16
    u16* buf16 = (u16*)(ws + off);    off += align256((size_t)N * D * 2);  // h1 as bf16

    dim3 b256(256);
    int nb = (N + 1023) / 1024;

    long zone4 = (long)(zone_bytes / 16);
    zero4_k<<<(int)((zone4 + 255) / 256), b256, 0, stream>>>((int4*)ws, zone4);
    xcast_k<<<(N * D / 4 + 255) / 256, b256, 0, stream>>>((const float4*)x, (uint2*)xb,
                                                          N * D / 4);
    count_deg_k<<<(E + 255) / 256, b256, 0, stream>>>(dst, cnt, E);
    scan1_k<<<nb, 1024, 0, stream>>>(cnt, row, partials, N);
    scan2_k<<<1, 128, 0, stream>>>(partials, blockoff, row + N, nb);
    scan3_k<<<(N + 255) / 256, b256, 0, stream>>>(row, cur, blockoff, cnt, dinv, N);
    fill_k<<<(E + 255) / 256, b256, 0, stream>>>(src, dst, dinv, cur, srcs, ew, E);

    // layer 1: buf16 = bf16( relu( (A @ x) @ W1 + b1 ) )
    layer_k<<<2560, b256, 0, stream>>>(xb, row, srcs, ew, dinv, W1, b1, nullptr, buf16, N);
    // layer 2: out = relu( (A @ buf16) @ W2 + b2 )
    layer_k<<<2560, b256, 0, stream>>>((const u32*)buf16, row, srcs, ew, dinv, W2, b2, out,
                                       nullptr, N);
}

// Round 5
// 370.106 us; speedup vs baseline: 2.0148x; 1.1314x over previous
//
#include <hip/hip_runtime.h>

#define D 64

typedef unsigned int u32;
typedef unsigned short u16;

__device__ __forceinline__ float bf_lo(u32 p) { return __uint_as_float(p << 16); }
__device__ __forceinline__ float bf_hi(u32 p) { return __uint_as_float(p & 0xffff0000u); }
__device__ __forceinline__ u32 bf_rne(float f) {
    u32 u = __float_as_uint(f);
    return (u + 0x7fffu + ((u >> 16) & 1u)) >> 16;
}

// ---------------- zero a contiguous int4 region ----------------
__global__ void zero4_k(int4* __restrict__ p, long n4) {
    long i = (long)blockIdx.x * blockDim.x + threadIdx.x;
    if (i < n4) p[i] = make_int4(0, 0, 0, 0);
}

// ---------------- fp32 -> packed bf16 cast (4 floats / thread) ----------------
__global__ void xcast_k(const float4* __restrict__ x, uint2* __restrict__ xb, int n4) {
    int i = blockIdx.x * blockDim.x + threadIdx.x;
    if (i < n4) {
        float4 v = x[i];
        uint2 o;
        o.x = bf_rne(v.x) | (bf_rne(v.y) << 16);
        o.y = bf_rne(v.z) | (bf_rne(v.w) << 16);
        xb[i] = o;
    }
}

// ---------------- degree count ----------------
__global__ void count_deg_k(const int* __restrict__ dst, int* __restrict__ cnt, int E) {
    int e = blockIdx.x * blockDim.x + threadIdx.x;
    if (e < E) atomicAdd(&cnt[dst[e]], 1);
}

// ---------------- grid scan of padded counts (pad = ceil((cnt+1)/16)*16) ------
__global__ __launch_bounds__(1024) void scan1_k(const int* __restrict__ cnt,
                                                int* __restrict__ row,
                                                int* __restrict__ partials, int N) {
    __shared__ int wsum[16];
    int t = threadIdx.x, wave = t >> 6, lane = t & 63;
    int i = blockIdx.x * 1024 + t;
    int v = (i < N) ? ((cnt[i] + 16) & ~15) : 0;  // +1 self-loop, pad to 16
    int x = v;
#pragma unroll
    for (int off = 1; off < 64; off <<= 1) {
        int y = __shfl_up(x, off, 64);
        if (lane >= off) x += y;
    }
    if (lane == 63) wsum[wave] = x;
    __syncthreads();
    if (wave == 0) {
        int s = (lane < 16) ? wsum[lane] : 0;
#pragma unroll
        for (int off = 1; off < 16; off <<= 1) {
            int y = __shfl_up(s, off, 64);
            if (lane >= off) s += y;
        }
        if (lane < 16) wsum[lane] = s;
    }
    __syncthreads();
    int woff = (wave > 0) ? wsum[wave - 1] : 0;
    if (i < N) row[i] = x + woff - v;
    if (t == 0) partials[blockIdx.x] = wsum[15];
}

__global__ __launch_bounds__(128) void scan2_k(const int* __restrict__ partials,
                                               int* __restrict__ blockoff,
                                               int* __restrict__ rowN, int nb) {
    __shared__ int s[128];
    int t = threadIdx.x;
    int v = (t < nb) ? partials[t] : 0;
    s[t] = v;
    __syncthreads();
    for (int off = 1; off < 128; off <<= 1) {
        int add = (t >= off) ? s[t - off] : 0;
        __syncthreads();
        s[t] += add;
        __syncthreads();
    }
    blockoff[t] = s[t] - v;
    if (t == nb - 1) *rowN = s[t];
}

// pass 3: finalize row, write self-loop edge, init cursor past it, compute dinv
__global__ void scan3_k(int* __restrict__ row, int* __restrict__ cur,
                        const int* __restrict__ blockoff,
                        const int* __restrict__ cnt, float* __restrict__ dinv,
                        int2* __restrict__ pr, int N) {
    int i = blockIdx.x * blockDim.x + threadIdx.x;
    if (i < N) {
        int r = row[i] + blockoff[i >> 10];
        row[i] = r;
        float di = rsqrtf((float)cnt[i] + 1.0f);
        dinv[i] = di;
        pr[r] = make_int2(i, __float_as_int(di * di));  // self-loop edge
        cur[i] = r + 1;
    }
}

// ---------------- CSR fill: pr[pos] = (src, dinv[s]*dinv[d]) ----------------
__global__ void fill_k(const int* __restrict__ src, const int* __restrict__ dst,
                       const float* __restrict__ dinv, int* __restrict__ cur,
                       int2* __restrict__ pr, int E) {
    int e = blockIdx.x * blockDim.x + threadIdx.x;
    if (e >= E) return;
    int s = src[e];
    int d = dst[e];
    int pos = atomicAdd(&cur[d], 1);
    pr[pos] = make_int2(s, __float_as_int(dinv[s] * dinv[d]));
}

// ---------------- fused layer: out = relu( (A_norm @ in) @ W + b ) ----------------
// wave per node. 16 lanes per gathered row: lane = (q = lane>>4, p = lane&15);
// quarter q handles edges 4e+q, lane loads uint2 = features 4p..4p+3.
__global__ __launch_bounds__(256) void layer_k(const uint2* __restrict__ inb2,
                                               const int* __restrict__ row,
                                               const int2* __restrict__ pr,
                                               const float* __restrict__ W,
                                               const float* __restrict__ b,
                                               float* __restrict__ out_f32,
                                               u16* __restrict__ out_b16, int N) {
    __shared__ float sW[D * D];
    __shared__ float sbias[D];
    int t = threadIdx.x;
    for (int i = t; i < D * D; i += 256) sW[i] = W[i];
    if (t < D) sbias[t] = b[t];
    __syncthreads();
    int lane = t & 63;
    int p = lane & 15;
    int q = lane >> 4;
    int wid = blockIdx.x * 4 + (t >> 6);
    int nw = gridDim.x * 4;
    for (int i = wid; i < N; i += nw) {
        int beg = row[i], end = row[i + 1];
        float v0 = 0.f, v1 = 0.f, v2 = 0.f, v3 = 0.f;
        for (int j = beg; j < end; j += 16) {
            int2 e0 = pr[j + q];
            int2 e1 = pr[j + 4 + q];
            int2 e2 = pr[j + 8 + q];
            int2 e3 = pr[j + 12 + q];
            uint2 g0 = inb2[(size_t)e0.x * 16 + p];
            uint2 g1 = inb2[(size_t)e1.x * 16 + p];
            uint2 g2 = inb2[(size_t)e2.x * 16 + p];
            uint2 g3 = inb2[(size_t)e3.x * 16 + p];
            float w0 = __int_as_float(e0.y);
            float w1 = __int_as_float(e1.y);
            float w2 = __int_as_float(e2.y);
            float w3 = __int_as_float(e3.y);
            v0 = fmaf(bf_lo(g0.x), w0, v0);
            v1 = fmaf(bf_hi(g0.x), w0, v1);
            v2 = fmaf(bf_lo(g0.y), w0, v2);
            v3 = fmaf(bf_hi(g0.y), w0, v3);
            v0 = fmaf(bf_lo(g1.x), w1, v0);
            v1 = fmaf(bf_hi(g1.x), w1, v1);
            v2 = fmaf(bf_lo(g1.y), w1, v2);
            v3 = fmaf(bf_hi(g1.y), w1, v3);
            v0 = fmaf(bf_lo(g2.x), w2, v0);
            v1 = fmaf(bf_hi(g2.x), w2, v1);
            v2 = fmaf(bf_lo(g2.y), w2, v2);
            v3 = fmaf(bf_hi(g2.y), w2, v3);
            v0 = fmaf(bf_lo(g3.x), w3, v0);
            v1 = fmaf(bf_hi(g3.x), w3, v1);
            v2 = fmaf(bf_lo(g3.y), w3, v2);
            v3 = fmaf(bf_hi(g3.y), w3, v3);
        }
        // sum the 4 quarters: features 4p..4p+3 complete in every lane after this
        v0 += __shfl_xor(v0, 16, 64);
        v1 += __shfl_xor(v1, 16, 64);
        v2 += __shfl_xor(v2, 16, 64);
        v3 += __shfl_xor(v3, 16, 64);
        v0 += __shfl_xor(v0, 32, 64);
        v1 += __shfl_xor(v1, 32, 64);
        v2 += __shfl_xor(v2, 32, 64);
        v3 += __shfl_xor(v3, 32, 64);
        // GEMM epilogue: feature k lives in component k&3 of lane k>>2
        float a0 = sbias[lane], a1 = 0.f, a2 = 0.f, a3 = 0.f;
#pragma unroll
        for (int k = 0; k < D; k += 4) {
            int sl = k >> 2;
            a0 = fmaf(__shfl(v0, sl, 64), sW[(k + 0) * D + lane], a0);
            a1 = fmaf(__shfl(v1, sl, 64), sW[(k + 1) * D + lane], a1);
            a2 = fmaf(__shfl(v2, sl, 64), sW[(k + 2) * D + lane], a2);
            a3 = fmaf(__shfl(v3, sl, 64), sW[(k + 3) * D + lane], a3);
        }
        float acc = fmaxf((a0 + a1) + (a2 + a3), 0.0f);
        if (out_b16) {
            out_b16[(size_t)i * D + lane] = (u16)bf_rne(acc);
        } else {
            out_f32[(size_t)i * D + lane] = acc;
        }
    }
}

// ---------------- launch ----------------

extern "C" void kernel_launch(void* const* d_in, const int* in_sizes, int n_in,
                              void* d_out, int out_size, void* d_ws, size_t ws_size,
                              hipStream_t stream) {
    const float* x  = (const float*)d_in[0];
    const int*   ei = (const int*)d_in[1];
    const float* W1 = (const float*)d_in[2];
    const float* b1 = (const float*)d_in[3];
    const float* W2 = (const float*)d_in[4];
    const float* b2 = (const float*)d_in[5];
    float* out = (float*)d_out;

    int N = in_sizes[0] / D;
    int E = in_sizes[1] / 2;
    const int* src = ei;
    const int* dst = ei + E;

    int Emax = E + 16 * N + 64;  // padded-CSR slot upper bound

    char* ws = (char*)d_ws;
    size_t off = 0;
    auto align256 = [](size_t v) { return (v + 255) & ~(size_t)255; };
    int* cnt = (int*)(ws + off);      off += align256((size_t)N * 4);
    int2* pr = (int2*)(ws + off);     off += align256((size_t)Emax * 8);
    size_t zone_bytes = off;          // cnt + pr zeroed together
    int* row = (int*)(ws + off);      off += align256((size_t)(N + 1) * 4);
    int* cur = (int*)(ws + off);      off += align256((size_t)N * 4);
    float* dinv = (float*)(ws + off); off += align256((size_t)N * 4);
    int* partials = (int*)(ws + off); off += 512;
    int* blockoff = (int*)(ws + off); off += 512;
    u32* xb = (u32*)(ws + off);       off += align256((size_t)N * D * 2);  // x bf16
    u16* buf16 = (u16*)(ws + off);    off += align256((size_t)N * D * 2);  // h1 bf16

    dim3 b256(256);
    int nb = (N + 1023) / 1024;

    long zone4 = (long)(zone_bytes / 16);
    zero4_k<<<(int)((zone4 + 255) / 256), b256, 0, stream>>>((int4*)ws, zone4);
    xcast_k<<<(N * D / 4 + 255) / 256, b256, 0, stream>>>((const float4*)x, (uint2*)xb,
                                                          N * D / 4);
    count_deg_k<<<(E + 255) / 256, b256, 0, stream>>>(dst, cnt, E);
    scan1_k<<<nb, 1024, 0, stream>>>(cnt, row, partials, N);
    scan2_k<<<1, 128, 0, stream>>>(partials, blockoff, row + N, nb);
    scan3_k<<<(N + 255) / 256, b256, 0, stream>>>(row, cur, blockoff, cnt, dinv, pr, N);
    fill_k<<<(E + 255) / 256, b256, 0, stream>>>(src, dst, dinv, cur, pr, E);

    // layer 1: buf16 = bf16( relu( (A @ x) @ W1 + b1 ) )
    layer_k<<<2560, b256, 0, stream>>>((const uint2*)xb, row, pr, W1, b1, nullptr, buf16, N);
    // layer 2: out = relu( (A @ buf16) @ W2 + b2 )
    layer_k<<<2560, b256, 0, stream>>>((const uint2*)buf16, row, pr, W2, b2, out, nullptr,
                                       N);
}